// Round 2
// baseline (1682.659 us; speedup 1.0000x reference)
//
#include <hip/hip_runtime.h>

// Soft-DTW, gamma=1.0, B=64, N=M=1024, log2-domain DP.
// One 256-thread block (4 waves, 1 wave/SIMD) per batch.
// Thread t owns matrix rows 4t..4t+3 in registers (diag vectors p1,p2).
// Neighbor exchange: __shfl_up within wave; LDS only for the 3 wave
// boundaries. Raw s_barrier + lgkmcnt-only wait per diagonal step keeps
// prefetched D loads (vmcnt) in flight across barriers.

#define BIGV 1.0e10f
#define LOG2E 1.4426950408889634f
#define LN2 0.6931471805599453f

constexpr int N = 1024;
constexpr int TPB = 256;
constexpr int R = 4;                   // rows per thread
constexpr int C = 8;                   // diagonals per superstep
constexpr int NW = TPB / 64;           // 4 waves
constexpr int NSUPER = (2 * N) / C;    // 256

__global__ __launch_bounds__(TPB)
void softdtw_kernel(const float* __restrict__ D, float* __restrict__ out) {
    const int b = blockIdx.x;
    const int t = threadIdx.x;
    const int lane = t & 63;
    const int wave = t >> 6;
    const int wprev = (wave > 0) ? wave - 1 : 0;
    const float* __restrict__ Db = D + (size_t)b * N * N;

    __shared__ float xb1[2][NW];
    __shared__ float xb2[2][NW];

    float p1[R], p2[R];
#pragma unroll
    for (int k = 0; k < R; ++k) { p1[k] = BIGV; p2[k] = BIGV; }

    const int r0 = t * R;

    if (lane == 63) { xb1[0][wave] = BIGV; xb2[0][wave] = BIGV; }

    float dA[R][C], dB[R][C];

    auto LOAD = [&](float (&dst)[R][C], int s) {
        const int dstart = 2 + s * C;
#pragma unroll
        for (int k = 0; k < R; ++k) {
            const int row = r0 + k;
            const int j0 = dstart - 2 - row;
#pragma unroll
            for (int c = 0; c < C; ++c) {
                int j = j0 + c;
                int jc = min(max(j, 0), N - 1);
                dst[k][c] = Db[(size_t)row * N + jc];
            }
        }
    };

    int par = 0;

    auto COMPUTE = [&](float (&dreg)[R][C], int dstart) {
#pragma unroll
        for (int c = 0; c < C; ++c) {
            const int d = dstart + c;
            if (d > 2 * N) break;

            // my boundary row (pre-update) for downward neighbor
            float bt1 = p1[R - 1], bt2 = p2[R - 1];

            // make this step's LDS writes (from last step) visible; do NOT
            // drain vmcnt — D prefetch stays in flight.
            asm volatile("s_waitcnt lgkmcnt(0)" ::: "memory");
            __builtin_amdgcn_s_barrier();
            asm volatile("" ::: "memory");

            float l1 = xb1[par][wprev];
            float l2 = xb2[par][wprev];
            float nb1 = __shfl_up(bt1, 1);
            float nb2 = __shfl_up(bt2, 1);
            if (lane == 0) { nb1 = l1; nb2 = l2; }
            if (t == 0) { nb1 = BIGV; nb2 = (d == 2) ? 0.0f : BIGV; }

            float np[R];
#pragma unroll
            for (int k = 0; k < R; ++k) {
                float a  = (k == 0) ? nb2 : p2[k - 1];   // v_{d-2}[i-1]
                float bb = (k == 0) ? nb1 : p1[k - 1];   // v_{d-1}[i-1]
                float cc = p1[k];                        // v_{d-1}[i]
                float mn = fminf(fminf(a, bb), cc);
                float ssum = exp2f(mn - a) + exp2f(mn - bb) + exp2f(mn - cc);
                float sm = mn - log2f(ssum);
                int j = d - 2 - (r0 + k);
                bool valid = ((unsigned)j < (unsigned)N);
                np[k] = valid ? fmaf(dreg[k][c], LOG2E, sm) : BIGV;
            }
#pragma unroll
            for (int k = 0; k < R; ++k) { p2[k] = p1[k]; p1[k] = np[k]; }

            if (lane == 63) {
                xb1[par ^ 1][wave] = p1[R - 1];
                xb2[par ^ 1][wave] = p2[R - 1];
            }
            par ^= 1;
        }
    };

    LOAD(dA, 0);
    for (int s = 0; s < NSUPER; s += 2) {
        LOAD(dB, s + 1);
        COMPUTE(dA, 2 + s * C);
        if (s + 2 < NSUPER) LOAD(dA, s + 2);
        COMPUTE(dB, 2 + (s + 1) * C);
    }

    // answer: v_{2N}[N] lives in thread 255 (row 1023), k=3; unscale by ln2
    if (t == TPB - 1) out[b] = p1[R - 1] * LN2;
}

extern "C" void kernel_launch(void* const* d_in, const int* in_sizes, int n_in,
                              void* d_out, int out_size, void* d_ws, size_t ws_size,
                              hipStream_t stream) {
    const float* D = (const float*)d_in[0];
    float* out = (float*)d_out;
    const int B = in_sizes[0] / (N * N);
    softdtw_kernel<<<B, TPB, 0, stream>>>(D, out);
}

// Round 3
// 573.882 us; speedup vs baseline: 2.9321x; 2.9321x over previous
//
#include <hip/hip_runtime.h>

// Soft-DTW, gamma=1.0, B=64, N=M=1024, log2-domain DP.
// Tiled wavefront pipeline: one 256-thread block per batch. Thread t owns
// DP rows [4t+1, 4t+4]; work proceeds in 8-column chunks; thread t handles
// chunk c at step s=t+c (383 barrier steps instead of 2047). Thread t passes
// {corner, bottom-row[8]} to t+1 via double-buffered LDS (stride 9 floats,
// conflict-free). D chunks (4 rows x 32B) double-buffered in registers,
// prefetched before the barrier (vmcnt stays in flight).

#define BIGV 1.0e10f
#define LOG2E 1.4426950408889634f
#define LN2 0.6931471805599453f

constexpr int N = 1024;
constexpr int TPB = 256;
constexpr int R = 4;               // rows per thread
constexpr int CW = 8;              // columns per chunk
constexpr int K = N / CW;          // 128 chunks
constexpr int S = TPB + K - 1;     // 383 pipeline steps

__device__ __forceinline__ float fexp2(float x) {
    float r; asm("v_exp_f32 %0, %1" : "=v"(r) : "v"(x)); return r;
}
__device__ __forceinline__ float flog2(float x) {
    float r; asm("v_log_f32 %0, %1" : "=v"(r) : "v"(x)); return r;
}

__global__ __launch_bounds__(TPB)
void softdtw_kernel(const float* __restrict__ D, float* __restrict__ out) {
    const int b = blockIdx.x;
    const int t = threadIdx.x;
    const float* __restrict__ Db = D + (size_t)b * N * N;
    const int i0 = t * R;          // first D row of my strip (0-based)

    __shared__ float buf[2][TPB * (CW + 1)];

    float L[R];                    // left boundary: R[i0+r+1][j0] running values
#pragma unroll
    for (int r = 0; r < R; ++r) L[r] = BIGV;

    float dA[R][CW], dB[R][CW];

    auto PREFETCH = [&](float (&dst)[R][CW], int cn) {
        const float* base = Db + (size_t)i0 * N + cn * CW;
#pragma unroll
        for (int r = 0; r < R; ++r) {
            float4 v0 = *(const float4*)(base + (size_t)r * N);
            float4 v1 = *(const float4*)(base + (size_t)r * N + 4);
            dst[r][0] = v0.x; dst[r][1] = v0.y; dst[r][2] = v0.z; dst[r][3] = v0.w;
            dst[r][4] = v1.x; dst[r][5] = v1.y; dst[r][6] = v1.z; dst[r][7] = v1.w;
        }
    };

    int par = 0;

    auto STEP = [&](int s, float (&cur)[R][CW], float (&nxt)[R][CW]) {
        const int cn = s + 1 - t;
        if (cn >= 0 && cn < K) PREFETCH(nxt, cn);

        // LDS writes/reads of previous step must be visible; do NOT drain
        // vmcnt — D prefetch stays in flight across the barrier.
        asm volatile("s_waitcnt lgkmcnt(0)" ::: "memory");
        __builtin_amdgcn_s_barrier();
        asm volatile("" ::: "memory");

        const int c = s - t;
        if (c >= 0 && c < K) {
            float T[CW + 1];       // T[0]=R[top][j0], T[m]=R[top][j0+m]
            if (t == 0) {
                T[0] = (c == 0) ? 0.0f : BIGV;   // R[0][0]=0, R[0][j>=1]=BIG
#pragma unroll
                for (int m = 1; m <= CW; ++m) T[m] = BIGV;
            } else {
#pragma unroll
                for (int m = 0; m <= CW; ++m)
                    T[m] = buf[par][(t - 1) * (CW + 1) + m];
            }

            float bout[CW + 1];
            bout[0] = L[R - 1];    // R[bottom][j0] before this chunk

#pragma unroll
            for (int m = 1; m <= CW; ++m) {
                float vprev = 0.0f, prevOld = 0.0f;
#pragma unroll
                for (int r = 0; r < R; ++r) {
                    float a  = (r == 0) ? T[m - 1] : prevOld;  // up-left
                    float bb = (r == 0) ? T[m]     : vprev;    // up
                    float cc = L[r];                           // left
                    float mn = fminf(fminf(a, bb), cc);
                    float ssum = fexp2(mn - a) + fexp2(mn - bb) + fexp2(mn - cc);
                    float sm = mn - flog2(ssum);
                    float v = fmaf(cur[r][m - 1], LOG2E, sm);
                    prevOld = cc;
                    vprev = v;
                    L[r] = v;
                }
                bout[m] = L[R - 1];
            }
#pragma unroll
            for (int m = 0; m <= CW; ++m)
                buf[par ^ 1][t * (CW + 1) + m] = bout[m];
        }
        par ^= 1;
    };

    if (t == 0) PREFETCH(dA, 0);
    for (int s = 0; s < S + 1; s += 2) {   // 384 steps (last is a no-op pad)
        STEP(s, dA, dB);
        STEP(s + 1, dB, dA);
    }

    // R[N][N] is thread 255's bottom-row running value; unscale from log2.
    if (t == TPB - 1) out[b] = L[R - 1] * LN2;
}

extern "C" void kernel_launch(void* const* d_in, const int* in_sizes, int n_in,
                              void* d_out, int out_size, void* d_ws, size_t ws_size,
                              hipStream_t stream) {
    const float* D = (const float*)d_in[0];
    float* out = (float*)d_out;
    const int B = in_sizes[0] / (N * N);
    softdtw_kernel<<<B, TPB, 0, stream>>>(D, out);
}

// Round 5
// 434.466 us; speedup vs baseline: 3.8729x; 1.3209x over previous
//
#include <hip/hip_runtime.h>

// Soft-DTW, gamma=1.0, B=64, N=M=1024, log2-domain DP.
// Pair-representation INSIDE each 4x4 tile: cell = (u, s), value v = u - log2(s),
// u = min3(u_a,u_b,u_c) + D*log2e, s = sum s_i * 2^(mn - u_i). Tile inputs are
// normalized (s=1), so s <= 3^7 in-tile (no overflow). Bottom row / right
// column are re-normalized (v = u - log2(s)) before export: 7 log2 per 16
// cells, and the u-chain (min3+fma, ~10cyc/level) is the only serial path.
//
// Tiled wavefront pipeline: 256 threads/block, one block per batch. Thread t
// owns padded rows 4t+1..4t+4; CW=4-column chunks; thread t runs chunk c at
// step s=t+c (511 steps). Bottom-row v's -> thread t+1 via double-buffered
// LDS (stride 5 floats: 2-way bank aliasing = free). D chunk (4x float4)
// double-buffered in registers; prefetch issued before the barrier and only
// lgkmcnt is drained, so vmcnt stays in flight across barriers.

#define BIGV 1.0e10f
#define LOG2E 1.4426950408889634f
#define LN2 0.6931471805599453f

constexpr int N = 1024;
constexpr int TPB = 256;
constexpr int R = 4;               // rows per thread
constexpr int CW = 4;              // columns per chunk
constexpr int K = N / CW;          // 256 chunks
constexpr int S = TPB + K - 1;     // 511 pipeline steps
constexpr int XW = CW + 1;         // 5-float stride in exchange buffer

__device__ __forceinline__ float fexp2(float x) {
    float r; asm("v_exp_f32 %0, %1" : "=v"(r) : "v"(x)); return r;
}
__device__ __forceinline__ float flog2(float x) {
    float r; asm("v_log_f32 %0, %1" : "=v"(r) : "v"(x)); return r;
}
__device__ __forceinline__ float fmin3(float a, float b, float c) {
    float r; asm("v_min3_f32 %0, %1, %2, %3" : "=v"(r) : "v"(a), "v"(b), "v"(c));
    return r;
}

__global__ __launch_bounds__(TPB)
void softdtw_kernel(const float* __restrict__ D, float* __restrict__ out) {
    const int b = blockIdx.x;
    const int t = threadIdx.x;
    const float* __restrict__ Db = D + (size_t)b * N * N;
    const int i0 = t * R;          // first D row (0-based)

    __shared__ float xch[2][TPB * XW];

    float Lv[R];                   // left boundary values (normalized)
#pragma unroll
    for (int r = 0; r < R; ++r) Lv[r] = BIGV;
    float Cv = (t == 0) ? 0.0f : BIGV;   // top-left corner value

    float dA[R][CW], dB[R][CW];
    auto PREFETCH = [&](float (&dst)[R][CW], int cn) {
        const float* base = Db + (size_t)i0 * N + cn * CW;
#pragma unroll
        for (int r = 0; r < R; ++r) {
            float4 v = *(const float4*)(base + (size_t)r * N);
            dst[r][0] = v.x; dst[r][1] = v.y; dst[r][2] = v.z; dst[r][3] = v.w;
        }
    };

    int par = 0;

    auto STEP = [&](int s, float (&cur)[R][CW], float (&nxt)[R][CW]) {
        const int cn = s + 1 - t;
        if (cn >= 0 && cn < K) PREFETCH(nxt, cn);

        // make prior LDS ops visible; do NOT drain vmcnt (D stays in flight)
        asm volatile("s_waitcnt lgkmcnt(0)" ::: "memory");
        __builtin_amdgcn_s_barrier();
        asm volatile("" ::: "memory");

        const int c = s - t;
        if (c >= 0 && c < K) {
            float Tv[CW + 1];      // top boundary values (normalized)
            Tv[0] = Cv;
            if (t == 0) {
#pragma unroll
                for (int m = 1; m <= CW; ++m) Tv[m] = BIGV;
            } else {
                const float* src = &xch[par][(t - 1) * XW];
#pragma unroll
                for (int m = 1; m <= CW; ++m) Tv[m] = src[m - 1];
            }
            Cv = Tv[CW];           // corner for my next chunk

            float Vu[R][CW], Vs[R][CW];
#pragma unroll
            for (int l = 0; l < R + CW - 1; ++l) {
#pragma unroll
                for (int r = 0; r < R; ++r) {
                    const int m = l - r;
                    if (m >= 0 && m < CW) {
                        // neighbor pairs; aOne/bOne/cOne are compile-time
                        const bool aOne = (r == 0) || (m == 0);
                        const bool bOne = (r == 0);
                        const bool cOne = (m == 0);
                        float ua = (r == 0) ? Tv[m]
                                 : ((m == 0) ? Lv[r - 1] : Vu[r - 1][m - 1]);
                        float sa = aOne ? 1.0f
                                 : Vs[r - 1][m - 1];
                        float ub = (r == 0) ? Tv[m + 1] : Vu[r - 1][m];
                        float sb = bOne ? 1.0f : Vs[r - 1][m];
                        float uc = (m == 0) ? Lv[r] : Vu[r][m - 1];
                        float sc = cOne ? 1.0f : Vs[r][m - 1];

                        float mn = fmin3(ua, ub, uc);
                        float ea = fexp2(mn - ua);
                        float eb = fexp2(mn - ub);
                        float ec = fexp2(mn - uc);
                        float sig = aOne ? ea : sa * ea;
                        sig = bOne ? (sig + eb) : fmaf(sb, eb, sig);
                        sig = cOne ? (sig + ec) : fmaf(sc, ec, sig);
                        float un = fmaf(cur[r][m], LOG2E, mn);
                        Vu[r][m] = un;
                        Vs[r][m] = sig;

                        // boundary normalization + early export
                        if (r == R - 1 || m == CW - 1) {
                            float vn = un - flog2(sig);
                            if (r == R - 1)
                                xch[par ^ 1][t * XW + m] = vn;
                            if (m == CW - 1)
                                Lv[r] = vn;   // safe: readers ran at levels <= l-2
                        }
                    }
                }
            }
        }
        par ^= 1;
    };

    if (t == 0) PREFETCH(dA, 0);
    for (int s = 0; s < S + 1; s += 2) {   // 512 steps (last is a no-op pad)
        STEP(s, dA, dB);
        STEP(s + 1, dB, dA);
    }

    // R[N][N] = thread 255's Lv[3] (already normalized); unscale from log2
    if (t == TPB - 1) out[b] = Lv[R - 1] * LN2;
}

extern "C" void kernel_launch(void* const* d_in, const int* in_sizes, int n_in,
                              void* d_out, int out_size, void* d_ws, size_t ws_size,
                              hipStream_t stream) {
    const float* D = (const float*)d_in[0];
    float* out = (float*)d_out;
    const int B = in_sizes[0] / (N * N);
    softdtw_kernel<<<B, TPB, 0, stream>>>(D, out);
}